// Round 7
// baseline (5147.845 us; speedup 1.0000x reference)
//
#include <hip/hip_runtime.h>
#include <hip/hip_bf16.h>

typedef __bf16 bf16_t;
typedef bf16_t bf16x8 __attribute__((ext_vector_type(8)));
typedef float f32x4 __attribute__((ext_vector_type(4)));
typedef unsigned long long u64;

#define T_SEQ 512
#define NB 128
#define HID 1024
#define FIN 64
#define HBH (64 * 1024)          // elems per half-batch h snapshot (128 KB)
#define NBLK 256                 // 64 L0 + 64 X1 + 128 L1
#define DM 32                    // master h ring depth (per chain)
#define DX 8                     // X1 partial ring depth (per chain)
#define X1SLOTH (4096 * 64)      // floats per X1 slot (half batch)

// Fragment-contiguous weight LDS: frag*1024B + lane*16B, conflict-free.
#define NF0 136                  // L0 frags: 34 k-chunks x 4 row-tiles
#define NF1 128                  // X1 frags: 32 x 4
#define NFR 64                   // L1 frags: 32 x 2
#define L0_STAGE (NF0 * 64 * 8)  // elems: 69632
#define L1_STAGE (NFR * 64 * 8)  // elems: 32768
// L0 LDS: weights 139264B + stage 2048B + cl 8192B = 149504B
#define LDS_BYTES 151552

// sync[]: per-block, per-chain completion flags (value = steps completed).
// F0c = c*64 (L0), FXc = 128 + c*64 (X1), F1c = 256 + c*128 (L1)
#define SYNC_N 512

__device__ __forceinline__ float sigm_f(float x) { return 1.0f / (1.0f + __expf(-x)); }
__device__ __forceinline__ float tanh_f(float x) { return 2.0f * sigm_f(2.0f * x) - 1.0f; }

__device__ __forceinline__ unsigned ldcnt(const unsigned* p) {
    return __hip_atomic_load(p, __ATOMIC_RELAXED, __HIP_MEMORY_SCOPE_AGENT);
}
__device__ __forceinline__ void stw32(unsigned* p, unsigned v) {
    __hip_atomic_store(p, v, __ATOMIC_RELAXED, __HIP_MEMORY_SCOPE_AGENT);
}
__device__ __forceinline__ void stwf(float* p, float v) {
    __hip_atomic_store(p, v, __ATOMIC_RELAXED, __HIP_MEMORY_SCOPE_AGENT);
}
__device__ __forceinline__ void stw64(u64* p, u64 v) {
    __hip_atomic_store(p, v, __ATOMIC_RELAXED, __HIP_MEMORY_SCOPE_AGENT);
}

// Half-batch fragment-swizzled h layout: 16B unit = (panel*4 + ntile)*64 + lane,
// holding h[n = ntile*16 + (lane&15)][k = panel*32 + (lane>>4)*8 .. +8].

__global__ __launch_bounds__(256) void prep_kernel(
    const float* __restrict__ x,
    const float* __restrict__ Wih0, const float* __restrict__ Whh0,
    const float* __restrict__ bih0, const float* __restrict__ bhh0,
    const float* __restrict__ Wih1, const float* __restrict__ Whh1,
    const float* __restrict__ bih1, const float* __restrict__ bhh1,
    const float* __restrict__ Wfc,
    bf16_t* __restrict__ Wf0, bf16_t* __restrict__ Wf1, bf16_t* __restrict__ WfR,
    bf16_t* __restrict__ xswz, bf16_t* __restrict__ Wfcb,
    float* __restrict__ bias0, float* __restrict__ bias1,
    bf16_t* __restrict__ mh0, bf16_t* __restrict__ mh1,
    unsigned* __restrict__ sync)
{
    const unsigned stride = gridDim.x * blockDim.x;
    const unsigned i0 = blockIdx.x * blockDim.x + threadIdx.x;

    for (unsigned i = i0; i < SYNC_N; i += stride) sync[i] = 0u;

    for (unsigned i = i0; i < 64u * NF0 * 64u; i += stride) {
        unsigned g0 = i / (NF0 * 64u), rem = i % (NF0 * 64u);
        unsigned f = rem >> 6, ln = rem & 63u;
        unsigned pc = f >> 2, mt = f & 3u;
        unsigned r = mt * 16u + (ln & 15u);
        unsigned row = (r & 3u) * HID + g0 * 16u + (r >> 2);
        unsigned k0 = pc * 32u + (ln >> 4) * 8u;
        bf16_t* dst = Wf0 + (size_t)i * 8;
#pragma unroll
        for (int e = 0; e < 8; ++e) {
            unsigned k = k0 + e;
            float v = (k < FIN) ? Wih0[(size_t)row * FIN + k]
                                : Whh0[(size_t)row * HID + (k - FIN)];
            dst[e] = (bf16_t)v;
        }
    }
    for (unsigned i = i0; i < 64u * NF1 * 64u; i += stride) {
        unsigned g = i >> 13, rem = i & 8191u;
        unsigned f = rem >> 6, ln = rem & 63u;
        unsigned pc = f >> 2, mt = f & 3u;
        unsigned r = mt * 16u + (ln & 15u);
        unsigned row = (r & 3u) * HID + g * 16u + (r >> 2);
        unsigned k0 = pc * 32u + (ln >> 4) * 8u;
        bf16_t* dst = Wf1 + (size_t)i * 8;
#pragma unroll
        for (int e = 0; e < 8; ++e)
            dst[e] = (bf16_t)Wih1[(size_t)row * HID + k0 + e];
    }
    for (unsigned i = i0; i < 128u * NFR * 64u; i += stride) {
        unsigned g1 = i >> 12, rem = i & 4095u;
        unsigned f = rem >> 6, ln = rem & 63u;
        unsigned pc = f >> 1, mt = f & 1u;
        unsigned r = mt * 16u + (ln & 15u);
        unsigned row = (r & 3u) * HID + g1 * 8u + (r >> 2);
        unsigned k0 = pc * 32u + (ln >> 4) * 8u;
        bf16_t* dst = WfR + (size_t)i * 8;
#pragma unroll
        for (int e = 0; e < 8; ++e)
            dst[e] = (bf16_t)Whh1[(size_t)row * HID + k0 + e];
    }
    // x, half-batch chain-major swizzle: g = t*16 + c*8 + p*4 + nt
    for (unsigned i = i0; i < 4194304u; i += stride) {
        unsigned e = i & 7u, unit = i >> 3;
        unsigned lane = unit & 63u, g = unit >> 6;
        unsigned nt = g & 3u, p = (g >> 2) & 1u, c = (g >> 3) & 1u, t = g >> 4;
        unsigned n = c * 64u + nt * 16u + (lane & 15u);
        unsigned k = p * 32u + (lane >> 4) * 8u + e;
        xswz[i] = (bf16_t)x[((size_t)n * T_SEQ + t) * FIN + k];
    }
    for (unsigned i = i0; i < 64u * HID; i += stride)
        Wfcb[i] = (bf16_t)Wfc[i];
    for (unsigned i = i0; i < (unsigned)(2 * DM * HBH); i += stride) {
        mh0[i] = (bf16_t)0.0f; mh1[i] = (bf16_t)0.0f;
    }
    for (unsigned i = i0; i < 4096u; i += stride) {
        bias0[i] = bih0[i] + bhh0[i];
        bias1[i] = bih1[i] + bhh1[i];
    }
}

// Persistent cooperative kernel, 256 blocks x 512 threads, 1 block/CU.
// BATCH-INTERLEAVE: batch rows 0-63 (chain A) and 64-127 (chain B) are
// independent recurrences sharing only the LDS-resident weights. Each step
// runs phase(A,t) then phase(B,t): while chain A's flags/data propagate
// cross-XCD (~1.2us), chain B computes -- polls become pre-satisfied.
// Per-phase wave grid 2m x 4n (L0/X1) keeps A-LDS and B-global traffic at
// R5 levels with no cross-wave reduction. Per-wave epilogues (wave-owned
// stage patch + lgkmcnt) -> 2 barriers/phase.
__global__ __launch_bounds__(512, 2) void lstm_persist(
    const bf16_t* __restrict__ Wf0, const bf16_t* __restrict__ Wf1,
    const bf16_t* __restrict__ WfR,
    const float* __restrict__ bias0, const float* __restrict__ bias1,
    const bf16_t* __restrict__ xswz,
    bf16_t* __restrict__ mh0, bf16_t* __restrict__ mh1,  // [2][DM][HBH]
    bf16_t* __restrict__ h2buf,
    float* __restrict__ x1r,                             // [2][DX][X1SLOTH]
    unsigned* __restrict__ sync)
{
    extern __shared__ bf16_t Wl[];
    const int b = blockIdx.x;
    const int tid = threadIdx.x;
    const int wv = tid >> 6;
    const int lane = tid & 63;
    const int q = lane >> 4;
    const int l = lane & 15;
    const int mh = wv >> 2;      // 0..1
    const int nh = wv & 3;       // 0..3

    if (b < 64) {
        // ================= L0: layer-0 recurrence =================
        const int g0 = b;
        for (int cc = tid; cc < NF0 * 64; cc += 512)
            *(bf16x8*)(Wl + (size_t)cc * 8) =
                *(const bf16x8*)(Wf0 + ((size_t)g0 * (NF0 * 64) + cc) * 8);
        bf16_t* stage = Wl + L0_STAGE;                    // [64 n][16 u]
        float* cl = (float*)(Wl + L0_STAGE + 1024);       // [16 u][128 n_glob]
        for (int i = tid; i < 16 * NB; i += 512) cl[i] = 0.0f;
        float bj[2][4];
#pragma unroll
        for (int mti = 0; mti < 2; ++mti) {
            const int j = g0 * 16 + (mh * 2 + mti) * 4 + q;
#pragma unroll
            for (int gg = 0; gg < 4; ++gg) bj[mti][gg] = bias0[gg * HID + j];
        }
        __syncthreads();

        for (int t = 0; t < T_SEQ; ++t) {
#pragma unroll
            for (int c = 0; c < 2; ++c) {
                f32x4 acc[2] = {{0.f,0.f,0.f,0.f},{0.f,0.f,0.f,0.f}};
                {   // x chunks (pc 0,1): no chain dependency, before the wait
                    const bf16_t* X = xswz + (size_t)(t * 2 + c) * 4096;
#pragma unroll
                    for (int p = 0; p < 2; ++p) {
                        bf16x8 bv  = *(const bf16x8*)(X + (((size_t)p * 4 + nh) * 64 + lane) * 8);
                        bf16x8 av0 = *(const bf16x8*)(Wl + ((size_t)(p * 4 + mh * 2) * 64 + lane) * 8);
                        bf16x8 av1 = *(const bf16x8*)(Wl + ((size_t)(p * 4 + mh * 2 + 1) * 64 + lane) * 8);
                        acc[0] = __builtin_amdgcn_mfma_f32_16x16x32_bf16(av0, bv, acc[0], 0, 0, 0);
                        acc[1] = __builtin_amdgcn_mfma_f32_16x16x32_bf16(av1, bv, acc[1], 0, 0, 0);
                    }
                }
                // wait: f0c all >= t (own chain); fXc all >= t-31 (slot reuse)
                if (wv == 0) {
                    const unsigned tA = (unsigned)t;
                    const unsigned tB = (t >= DM) ? (unsigned)(t - (DM - 1)) : 0u;
                    const unsigned* f0c = sync + c * 64;
                    const unsigned* fxc = sync + 128 + c * 64;
                    for (;;) {
                        bool ok = (ldcnt(&f0c[lane]) >= tA) && (ldcnt(&fxc[lane]) >= tB);
                        if (__all(ok)) break;
                        __builtin_amdgcn_s_sleep(1);
                    }
                }
                __syncthreads();
                // h chunks from mh0[c][t-1]
                {
                    const bf16_t* B = mh0 + ((size_t)c * DM + ((t + DM - 1) & (DM - 1))) * HBH;
                    bf16x8 bb[16];
#pragma unroll
                    for (int i = 0; i < 16; ++i)
                        bb[i] = *(const bf16x8*)(B + (((size_t)i * 4 + nh) * 64 + lane) * 8);
#pragma unroll
                    for (int p = 0; p < 32; ++p) {
                        bf16x8 av0 = *(const bf16x8*)(Wl + ((size_t)((2 + p) * 4 + mh * 2) * 64 + lane) * 8);
                        bf16x8 av1 = *(const bf16x8*)(Wl + ((size_t)((2 + p) * 4 + mh * 2 + 1) * 64 + lane) * 8);
                        acc[0] = __builtin_amdgcn_mfma_f32_16x16x32_bf16(av0, bb[p & 15], acc[0], 0, 0, 0);
                        acc[1] = __builtin_amdgcn_mfma_f32_16x16x32_bf16(av1, bb[p & 15], acc[1], 0, 0, 0);
                        if (p + 16 < 32)
                            bb[p & 15] = *(const bf16x8*)(B + (((size_t)(p + 16) * 4 + nh) * 64 + lane) * 8);
                    }
                }
                // cell update -> wave-owned stage patch
#pragma unroll
                for (int mti = 0; mti < 2; ++mti) {
                    const int u = (mh * 2 + mti) * 4 + q;
                    const int n = nh * 16 + l;
                    float iv = sigm_f(acc[mti][0] + bj[mti][0]);
                    float fv = sigm_f(acc[mti][1] + bj[mti][1]);
                    float gv = tanh_f(acc[mti][2] + bj[mti][2]);
                    float ov = sigm_f(acc[mti][3] + bj[mti][3]);
                    const int ci = u * NB + c * 64 + n;
                    float cn = fv * cl[ci] + iv * gv;
                    cl[ci] = cn;
                    stage[n * 16 + u] = (bf16_t)(ov * tanh_f(cn));
                }
                __asm__ volatile("s_waitcnt lgkmcnt(0)" ::: "memory");
                if (q < 2) {   // per-wave master write (32 lanes/wave)
                    const int ug = mh * 2 + q;
                    const int n = nh * 16 + l;
                    u64 v = *(const u64*)(stage + n * 16 + ug * 4);
                    const int j0 = g0 * 16 + ug * 4;
                    size_t unit = (((size_t)(j0 >> 5)) * 4 + nh) * 64 + ((j0 >> 3) & 3) * 16 + l;
                    u64* ring = (u64*)(mh0 + ((size_t)c * DM + (t & (DM - 1))) * HBH);
                    stw64(ring + unit * 2 + ((j0 & 7) >> 2), v);
                }
                __syncthreads();   // drain all waves' stores (vmcnt 0 at barrier)
                if (tid == 0) stw32(&sync[c * 64 + g0], (unsigned)(t + 1));
            }
        }
    } else if (b < 128) {
        // ================= X1: W_ih1 @ h0[t] partials =================
        const int g = b - 64;
        for (int cc = tid; cc < NF1 * 64; cc += 512)
            *(bf16x8*)(Wl + (size_t)cc * 8) =
                *(const bf16x8*)(Wf1 + ((size_t)g * (NF1 * 64) + cc) * 8);
        __syncthreads();

        for (int t = 0; t < T_SEQ; ++t) {
#pragma unroll
            for (int c = 0; c < 2; ++c) {
                // wait: f0c all >= t+1 (h0[t]); f1c all >= t-(DX-1) (ring guard)
                if (wv == 0) {
                    const unsigned tA = (unsigned)(t + 1);
                    const unsigned tC = (t >= DX) ? (unsigned)(t - (DX - 1)) : 0u;
                    const unsigned* f0c = sync + c * 64;
                    const unsigned* f1c = sync + 256 + c * 128;
                    for (;;) {
                        bool ok = (ldcnt(&f0c[lane]) >= tA)
                               && (ldcnt(&f1c[lane]) >= tC)
                               && (ldcnt(&f1c[64 + lane]) >= tC);
                        if (__all(ok)) break;
                        __builtin_amdgcn_s_sleep(1);
                    }
                }
                __syncthreads();
                f32x4 acc[2] = {{0.f,0.f,0.f,0.f},{0.f,0.f,0.f,0.f}};
                {
                    const bf16_t* B = mh0 + ((size_t)c * DM + (t & (DM - 1))) * HBH;
                    bf16x8 bb[16];
#pragma unroll
                    for (int i = 0; i < 16; ++i)
                        bb[i] = *(const bf16x8*)(B + (((size_t)i * 4 + nh) * 64 + lane) * 8);
#pragma unroll
                    for (int p = 0; p < 32; ++p) {
                        bf16x8 av0 = *(const bf16x8*)(Wl + ((size_t)(p * 4 + mh * 2) * 64 + lane) * 8);
                        bf16x8 av1 = *(const bf16x8*)(Wl + ((size_t)(p * 4 + mh * 2 + 1) * 64 + lane) * 8);
                        acc[0] = __builtin_amdgcn_mfma_f32_16x16x32_bf16(av0, bb[p & 15], acc[0], 0, 0, 0);
                        acc[1] = __builtin_amdgcn_mfma_f32_16x16x32_bf16(av1, bb[p & 15], acc[1], 0, 0, 0);
                        if (p + 16 < 32)
                            bb[p & 15] = *(const bf16x8*)(B + (((size_t)(p + 16) * 4 + nh) * 64 + lane) * 8);
                    }
                }
                {   // scatter partials (write-through f32)
                    float* P = x1r + ((size_t)c * DX + (t & (DX - 1))) * X1SLOTH + (size_t)g * 64 * 64;
                    const int n = nh * 16 + l;
#pragma unroll
                    for (int mti = 0; mti < 2; ++mti) {
                        const int u = (mh * 2 + mti) * 4 + q;
#pragma unroll
                        for (int jj = 0; jj < 4; ++jj)
                            stwf(P + (size_t)(u * 4 + jj) * 64 + n, acc[mti][jj]);
                    }
                }
                __syncthreads();   // drain partial stores
                if (tid == 0) stw32(&sync[128 + c * 64 + g], (unsigned)(t + 1));
            }
        }
    } else {
        // ================= L1: layer-1 recurrent half =================
        const int g1 = b - 128;
        for (int cc = tid; cc < NFR * 64; cc += 512)
            *(bf16x8*)(Wl + (size_t)cc * 8) =
                *(const bf16x8*)(WfR + ((size_t)g1 * (NFR * 64) + cc) * 8);
        bf16_t* stage = Wl + L1_STAGE;                    // [64 n][8 u]
        float* cl = (float*)(Wl + L1_STAGE + 512);        // [8 u][128 n_glob]
        for (int i = tid; i < 8 * NB; i += 512) cl[i] = 0.0f;
        float bj[4];
        {
            const int j = g1 * 8 + mh * 4 + q;
#pragma unroll
            for (int gg = 0; gg < 4; ++gg) bj[gg] = bias1[gg * HID + j];
        }
        __syncthreads();

        for (int t = 0; t < T_SEQ; ++t) {
#pragma unroll
            for (int c = 0; c < 2; ++c) {
                // wait: fXc[g1>>1] >= t+1 (partials); f1c all >= t (own chain)
                if (wv == 0) {
                    const unsigned tA = (unsigned)(t + 1);
                    const unsigned tO = (unsigned)t;
                    const unsigned* fxc = sync + 128 + c * 64;
                    const unsigned* f1c = sync + 256 + c * 128;
                    const unsigned gx = (unsigned)(g1 >> 1);
                    for (;;) {
                        bool ok = (ldcnt(&fxc[gx]) >= tA)
                               && (ldcnt(&f1c[lane]) >= tO)
                               && (ldcnt(&f1c[64 + lane]) >= tO);
                        if (__all(ok)) break;
                        __builtin_amdgcn_s_sleep(1);
                    }
                }
                __syncthreads();
                // partials early (latency hides under the panel loop)
                float pv[4];
                {
                    const float* P = x1r + ((size_t)c * DX + (t & (DX - 1))) * X1SLOTH + (size_t)g1 * 32 * 64;
#pragma unroll
                    for (int jj = 0; jj < 4; ++jj)
                        pv[jj] = P[(size_t)((mh * 4 + q) * 4 + jj) * 64 + nh * 16 + l];
                }
                f32x4 acc = {0.f, 0.f, 0.f, 0.f};
                {
                    const bf16_t* B = mh1 + ((size_t)c * DM + ((t + DM - 1) & (DM - 1))) * HBH;
                    bf16x8 bb[16];
#pragma unroll
                    for (int i = 0; i < 16; ++i)
                        bb[i] = *(const bf16x8*)(B + (((size_t)i * 4 + nh) * 64 + lane) * 8);
#pragma unroll
                    for (int p = 0; p < 32; ++p) {
                        bf16x8 av = *(const bf16x8*)(Wl + ((size_t)(p * 2 + mh) * 64 + lane) * 8);
                        acc = __builtin_amdgcn_mfma_f32_16x16x32_bf16(av, bb[p & 15], acc, 0, 0, 0);
                        if (p + 16 < 32)
                            bb[p & 15] = *(const bf16x8*)(B + (((size_t)(p + 16) * 4 + nh) * 64 + lane) * 8);
                    }
                }
                {
                    const int u = mh * 4 + q;
                    const int n = nh * 16 + l;
                    float iv = sigm_f(acc[0] + pv[0] + bj[0]);
                    float fv = sigm_f(acc[1] + pv[1] + bj[1]);
                    float gv = tanh_f(acc[2] + pv[2] + bj[2]);
                    float ov = sigm_f(acc[3] + pv[3] + bj[3]);
                    const int ci = u * NB + c * 64 + n;
                    float cn = fv * cl[ci] + iv * gv;
                    cl[ci] = cn;
                    stage[n * 8 + u] = (bf16_t)(ov * tanh_f(cn));
                }
                __asm__ volatile("s_waitcnt lgkmcnt(0)" ::: "memory");
                if (q == 0) {   // per-wave master + h2 write (16 lanes/wave)
                    const int n = nh * 16 + l;
                    u64 v = *(const u64*)(stage + n * 8 + mh * 4);
                    const int j0 = g1 * 8 + mh * 4;
                    size_t unit = (((size_t)(j0 >> 5)) * 4 + nh) * 64 + ((j0 >> 3) & 3) * 16 + l;
                    u64* ring = (u64*)(mh1 + ((size_t)c * DM + (t & (DM - 1))) * HBH);
                    stw64(ring + unit * 2 + ((j0 & 7) >> 2), v);
                    *(u64*)(h2buf + ((size_t)(c * 64 + n) * T_SEQ + t) * HID + g1 * 8 + mh * 4) = v;
                }
                __syncthreads();   // drain
                if (tid == 0) stw32(&sync[256 + c * 128 + g1], (unsigned)(t + 1));
            }
        }
    }
}

__global__ __launch_bounds__(256) void fc_kernel(
    const bf16_t* __restrict__ h2buf, const bf16_t* __restrict__ Wfcb,
    const float* __restrict__ bfc, float* __restrict__ out)
{
    const int tid = threadIdx.x, wv = tid >> 6, lane = tid & 63;
    const int q = lane >> 4, l = lane & 15;
    const int m0 = blockIdx.x * 64 + wv * 16;
    const bf16_t* arow = h2buf + (size_t)(m0 + l) * HID + q * 8;
    const bf16_t* brow = Wfcb + (size_t)l * HID + q * 8;
    f32x4 acc[4] = {{0.f,0.f,0.f,0.f},{0.f,0.f,0.f,0.f},{0.f,0.f,0.f,0.f},{0.f,0.f,0.f,0.f}};
#pragma unroll 4
    for (int p = 0; p < 32; ++p) {
        bf16x8 av = *(const bf16x8*)(arow + p * 32);
#pragma unroll
        for (int ntile = 0; ntile < 4; ++ntile) {
            bf16x8 bv = *(const bf16x8*)(brow + (size_t)ntile * 16 * HID + p * 32);
            acc[ntile] = __builtin_amdgcn_mfma_f32_16x16x32_bf16(av, bv, acc[ntile], 0, 0, 0);
        }
    }
#pragma unroll
    for (int ntile = 0; ntile < 4; ++ntile) {
        float bv = bfc[ntile * 16 + l];
#pragma unroll
        for (int r = 0; r < 4; ++r)
            out[(size_t)(m0 + q * 4 + r) * 64 + ntile * 16 + l] = acc[ntile][r] + bv;
    }
}

extern "C" void kernel_launch(void* const* d_in, const int* in_sizes, int n_in,
                              void* d_out, int out_size, void* d_ws, size_t ws_size,
                              hipStream_t stream)
{
    const float* x    = (const float*)d_in[0];
    const float* Wih0 = (const float*)d_in[1];
    const float* Whh0 = (const float*)d_in[2];
    const float* bih0 = (const float*)d_in[3];
    const float* bhh0 = (const float*)d_in[4];
    const float* Wih1 = (const float*)d_in[5];
    const float* Whh1 = (const float*)d_in[6];
    const float* bih1 = (const float*)d_in[7];
    const float* bhh1 = (const float*)d_in[8];
    const float* Wfc  = (const float*)d_in[9];
    const float* bfc  = (const float*)d_in[10];
    float* out = (float*)d_out;

    char* ws = (char*)d_ws;
    size_t off = 0;
    auto alloc = [&](size_t bytes) -> void* {
        void* p = ws + off;
        off += (bytes + 255) & ~(size_t)255;
        return p;
    };
    bf16_t* Wf0  = (bf16_t*)alloc((size_t)64 * NF0 * 64 * 8 * 2);
    bf16_t* Wf1  = (bf16_t*)alloc((size_t)64 * NF1 * 64 * 8 * 2);
    bf16_t* WfR  = (bf16_t*)alloc((size_t)128 * NFR * 64 * 8 * 2);
    bf16_t* xswz = (bf16_t*)alloc((size_t)NB * T_SEQ * FIN * 2);
    bf16_t* h2buf= (bf16_t*)alloc((size_t)NB * T_SEQ * HID * 2);
    bf16_t* mh0  = (bf16_t*)alloc((size_t)2 * DM * HBH * 2);
    bf16_t* mh1  = (bf16_t*)alloc((size_t)2 * DM * HBH * 2);
    float*  x1r  = (float*)alloc((size_t)2 * DX * X1SLOTH * 4);
    float*  bias0= (float*)alloc(4096 * 4);
    float*  bias1= (float*)alloc(4096 * 4);
    bf16_t* Wfcb = (bf16_t*)alloc((size_t)64 * HID * 2);
    unsigned* syncp = (unsigned*)alloc(SYNC_N * 4);
    if (off > ws_size) return;

    hipFuncSetAttribute((const void*)lstm_persist,
                        hipFuncAttributeMaxDynamicSharedMemorySize, LDS_BYTES);

    prep_kernel<<<1024, 256, 0, stream>>>(x, Wih0, Whh0, bih0, bhh0,
                                          Wih1, Whh1, bih1, bhh1, Wfc,
                                          Wf0, Wf1, WfR, xswz, Wfcb,
                                          bias0, bias1, mh0, mh1, syncp);

    void* args[] = { (void*)&Wf0, (void*)&Wf1, (void*)&WfR,
                     (void*)&bias0, (void*)&bias1,
                     (void*)&xswz, (void*)&mh0, (void*)&mh1,
                     (void*)&h2buf, (void*)&x1r,
                     (void*)&syncp };
    hipLaunchCooperativeKernel((void*)lstm_persist, dim3(NBLK), dim3(512),
                               args, LDS_BYTES, stream);

    fc_kernel<<<(NB * T_SEQ) / 64, 256, 0, stream>>>(h2buf, Wfcb, bfc, out);
}

// Round 8
// 4999.655 us; speedup vs baseline: 1.0296x; 1.0296x over previous
//
#include <hip/hip_runtime.h>
#include <hip/hip_bf16.h>

typedef __bf16 bf16_t;
typedef bf16_t bf16x8 __attribute__((ext_vector_type(8)));
typedef float f32x4 __attribute__((ext_vector_type(4)));
typedef unsigned long long u64;

#define T_SEQ 512
#define NB 128
#define HID 1024
#define FIN 64
#define HB (NB * HID)            // 131072 elems = 256 KB per h snapshot
#define NBLK 256                 // 64 L0 + 64 X1 + 128 L1
#define DM 32                    // master h ring depth
#define DX 8                     // X1 partial ring depth
#define X1SLOT (4096 * NB)

// Fragment-contiguous weight LDS: frag*1024B + lane*16B, conflict-free.
#define NF0 136                  // L0 frags: 34 k-chunks x 4 row-tiles
#define NF1 128                  // X1 frags: 32 x 4
#define NFR 64                   // L1 frags: 32 x 2
#define L0_STAGE (NF0 * 64 * 8)  // elems: 69632
#define L1_STAGE (NFR * 64 * 8)  // elems: 32768
// L0 LDS: weights 139264B + stage 4096B + cl 8192B = 151552B
#define LDS_BYTES 151552

#define F0 0      // f0[64]:  L0 block flags
#define FX 64     // fX[64]:  X1 block flags
#define F1 128    // f1[128]: L1 block flags
#define SYNC_N 256

__device__ __forceinline__ float sigm_f(float x) { return 1.0f / (1.0f + __expf(-x)); }
__device__ __forceinline__ float tanh_f(float x) { return 2.0f * sigm_f(2.0f * x) - 1.0f; }

__device__ __forceinline__ unsigned ldcnt(const unsigned* p) {
    return __hip_atomic_load(p, __ATOMIC_RELAXED, __HIP_MEMORY_SCOPE_AGENT);
}
__device__ __forceinline__ void stw32(unsigned* p, unsigned v) {
    __hip_atomic_store(p, v, __ATOMIC_RELAXED, __HIP_MEMORY_SCOPE_AGENT);
}
__device__ __forceinline__ void stwf(float* p, float v) {
    __hip_atomic_store(p, v, __ATOMIC_RELAXED, __HIP_MEMORY_SCOPE_AGENT);
}
__device__ __forceinline__ void stw64(u64* p, u64 v) {
    __hip_atomic_store(p, v, __ATOMIC_RELAXED, __HIP_MEMORY_SCOPE_AGENT);
}

// Volatile-asm 16B global load: compiler cannot compress/reorder the stream,
// so all 32 panel loads stay in flight (the C++ version collapsed to depth
// ~4: VGPR_Count 52/88/68 across R1-R6 regardless of declared buffers).
#define GLOAD16(dst, addr) \
    asm volatile("global_load_dwordx4 %0, %1, off" : "=v"(dst) : "v"(addr))

// Fragment-swizzled h layout: 16B unit = (panel*8 + ntile)*64 + lane, holding
// h[n = ntile*16 + (lane&15)][k = panel*32 + (lane>>4)*8 .. +8].

__global__ __launch_bounds__(256) void prep_kernel(
    const float* __restrict__ x,
    const float* __restrict__ Wih0, const float* __restrict__ Whh0,
    const float* __restrict__ bih0, const float* __restrict__ bhh0,
    const float* __restrict__ Wih1, const float* __restrict__ Whh1,
    const float* __restrict__ bih1, const float* __restrict__ bhh1,
    const float* __restrict__ Wfc,
    bf16_t* __restrict__ Wf0, bf16_t* __restrict__ Wf1, bf16_t* __restrict__ WfR,
    bf16_t* __restrict__ xswz, bf16_t* __restrict__ Wfcb,
    float* __restrict__ bias0, float* __restrict__ bias1,
    bf16_t* __restrict__ mh0, bf16_t* __restrict__ mh1,
    unsigned* __restrict__ sync)
{
    const unsigned stride = gridDim.x * blockDim.x;
    const unsigned i0 = blockIdx.x * blockDim.x + threadIdx.x;

    for (unsigned i = i0; i < SYNC_N; i += stride) sync[i] = 0u;

    for (unsigned i = i0; i < 64u * NF0 * 64u; i += stride) {
        unsigned g0 = i / (NF0 * 64u), rem = i % (NF0 * 64u);
        unsigned f = rem >> 6, ln = rem & 63u;
        unsigned pc = f >> 2, mt = f & 3u;
        unsigned r = mt * 16u + (ln & 15u);
        unsigned row = (r & 3u) * HID + g0 * 16u + (r >> 2);
        unsigned k0 = pc * 32u + (ln >> 4) * 8u;
        bf16_t* dst = Wf0 + (size_t)i * 8;
#pragma unroll
        for (int e = 0; e < 8; ++e) {
            unsigned k = k0 + e;
            float v = (k < FIN) ? Wih0[(size_t)row * FIN + k]
                                : Whh0[(size_t)row * HID + (k - FIN)];
            dst[e] = (bf16_t)v;
        }
    }
    for (unsigned i = i0; i < 64u * NF1 * 64u; i += stride) {
        unsigned g = i >> 13, rem = i & 8191u;
        unsigned f = rem >> 6, ln = rem & 63u;
        unsigned pc = f >> 2, mt = f & 3u;
        unsigned r = mt * 16u + (ln & 15u);
        unsigned row = (r & 3u) * HID + g * 16u + (r >> 2);
        unsigned k0 = pc * 32u + (ln >> 4) * 8u;
        bf16_t* dst = Wf1 + (size_t)i * 8;
#pragma unroll
        for (int e = 0; e < 8; ++e)
            dst[e] = (bf16_t)Wih1[(size_t)row * HID + k0 + e];
    }
    for (unsigned i = i0; i < 128u * NFR * 64u; i += stride) {
        unsigned g1 = i >> 12, rem = i & 4095u;
        unsigned f = rem >> 6, ln = rem & 63u;
        unsigned pc = f >> 1, mt = f & 1u;
        unsigned r = mt * 16u + (ln & 15u);
        unsigned row = (r & 3u) * HID + g1 * 8u + (r >> 2);
        unsigned k0 = pc * 32u + (ln >> 4) * 8u;
        bf16_t* dst = WfR + (size_t)i * 8;
#pragma unroll
        for (int e = 0; e < 8; ++e)
            dst[e] = (bf16_t)Whh1[(size_t)row * HID + k0 + e];
    }
    for (unsigned i = i0; i < 4194304u; i += stride) {
        unsigned e = i & 7u, unit = i >> 3;
        unsigned lane = unit & 63u, g = unit >> 6;
        unsigned wvv = g & 7u, pt = g >> 3;
        unsigned p = pt & 1u, t = pt >> 1;
        unsigned n = wvv * 16u + (lane & 15u);
        unsigned k = p * 32u + (lane >> 4) * 8u + e;
        xswz[i] = (bf16_t)x[((size_t)n * T_SEQ + t) * FIN + k];
    }
    for (unsigned i = i0; i < 64u * HID; i += stride)
        Wfcb[i] = (bf16_t)Wfc[i];
    for (unsigned i = i0; i < (unsigned)(DM * HB); i += stride) {
        mh0[i] = (bf16_t)0.0f; mh1[i] = (bf16_t)0.0f;
    }
    for (unsigned i = i0; i < 4096u; i += stride) {
        bias0[i] = bih0[i] + bhh0[i];
        bias1[i] = bih1[i] + bhh1[i];
    }
}

// Persistent cooperative kernel, 256 blocks x 512 threads, 1 block/CU.
// R2 structure (whole-step wv0 polls, Mw64/Nw16 mapping) with the h-panel
// streams forced to depth-32 via volatile-asm global_load_dwordx4 + counted
// s_waitcnt vmcnt(16)/vmcnt(0) (hipcc collapsed every C++-level prefetch
// buffer to depth ~4, leaving ~34 L3-latency exposures per step on the chain).
__global__ __launch_bounds__(512, 2) void lstm_persist(
    const bf16_t* __restrict__ Wf0, const bf16_t* __restrict__ Wf1,
    const bf16_t* __restrict__ WfR,
    const float* __restrict__ bias0, const float* __restrict__ bias1,
    const bf16_t* __restrict__ xswz,
    bf16_t* __restrict__ mh0, bf16_t* __restrict__ mh1,
    bf16_t* __restrict__ h2buf,
    float* __restrict__ x1r,
    unsigned* __restrict__ sync)
{
    extern __shared__ bf16_t Wl[];
    const int b = blockIdx.x;
    const int tid = threadIdx.x;
    const int wv = tid >> 6;
    const int lane = tid & 63;
    const int q = lane >> 4;
    const int l = lane & 15;
    const int nn = wv * 16 + l;

    if (b < 64) {
        // ================= L0: layer-0 recurrence =================
        const int g0 = b;
        for (int c = tid; c < NF0 * 64; c += 512)
            *(bf16x8*)(Wl + (size_t)c * 8) =
                *(const bf16x8*)(Wf0 + ((size_t)g0 * (NF0 * 64) + c) * 8);
        bf16_t* stage = Wl + L0_STAGE;
        float* cl = (float*)(Wl + L0_STAGE + 2048);      // [16][NB]
        for (int i = tid; i < 16 * NB; i += 512) cl[i] = 0.0f;
        float bj[4][4];
#pragma unroll
        for (int mt = 0; mt < 4; ++mt) {
            const int j = g0 * 16 + mt * 4 + q;
#pragma unroll
            for (int gg = 0; gg < 4; ++gg) bj[mt][gg] = bias0[gg * HID + j];
        }
        __syncthreads();

        for (int t = 0; t < T_SEQ; ++t) {
            f32x4 acc[4] = {{0.f,0.f,0.f,0.f},{0.f,0.f,0.f,0.f},{0.f,0.f,0.f,0.f},{0.f,0.f,0.f,0.f}};
            {   // x panels: no dependency, before the wait
                const bf16_t* X = xswz + (size_t)t * 8192;
#pragma unroll
                for (int p = 0; p < 2; ++p) {
                    bf16x8 bv = *(const bf16x8*)(X + (((size_t)p * 8 + wv) * 64 + lane) * 8);
#pragma unroll
                    for (int mt = 0; mt < 4; ++mt) {
                        bf16x8 av = *(const bf16x8*)(Wl + ((size_t)(p * 4 + mt) * 64 + lane) * 8);
                        acc[mt] = __builtin_amdgcn_mfma_f32_16x16x32_bf16(av, bv, acc[mt], 0, 0, 0);
                    }
                }
            }
            // wait: f0 all >= t (own chain); fX all >= t-31 (mh0 slot reuse)
            if (wv == 0) {
                const unsigned tA = (unsigned)t;
                const unsigned tB = (t >= DM) ? (unsigned)(t - (DM - 1)) : 0u;
                for (;;) {
                    bool ok = (ldcnt(&sync[F0 + lane]) >= tA)
                           && (ldcnt(&sync[FX + lane]) >= tB);
                    if (__all(ok)) break;
                    __builtin_amdgcn_s_sleep(1);
                }
            }
            __syncthreads();
            // h panels from mh0[t-1]: depth-32 asm stream, split counted waits
            {
                const bf16_t* B = mh0 + (size_t)((t + DM - 1) & (DM - 1)) * HB;
                f32x4 bb[32];
#pragma unroll
                for (int i = 0; i < 32; ++i) {
                    const bf16_t* a = B + (((size_t)i * 8 + wv) * 64 + lane) * 8;
                    GLOAD16(bb[i], a);
                }
                asm volatile("s_waitcnt vmcnt(16)" ::: "memory");
                __builtin_amdgcn_sched_barrier(0);
#pragma unroll
                for (int p = 0; p < 16; ++p) {
                    bf16x8 bv = __builtin_bit_cast(bf16x8, bb[p]);
#pragma unroll
                    for (int mt = 0; mt < 4; ++mt) {
                        bf16x8 av = *(const bf16x8*)(Wl + ((size_t)((2 + p) * 4 + mt) * 64 + lane) * 8);
                        acc[mt] = __builtin_amdgcn_mfma_f32_16x16x32_bf16(av, bv, acc[mt], 0, 0, 0);
                    }
                }
                asm volatile("s_waitcnt vmcnt(0)" ::: "memory");
                __builtin_amdgcn_sched_barrier(0);
#pragma unroll
                for (int p = 16; p < 32; ++p) {
                    bf16x8 bv = __builtin_bit_cast(bf16x8, bb[p]);
#pragma unroll
                    for (int mt = 0; mt < 4; ++mt) {
                        bf16x8 av = *(const bf16x8*)(Wl + ((size_t)((2 + p) * 4 + mt) * 64 + lane) * 8);
                        acc[mt] = __builtin_amdgcn_mfma_f32_16x16x32_bf16(av, bv, acc[mt], 0, 0, 0);
                    }
                }
            }
            // cell update (c in LDS) -> stage
#pragma unroll
            for (int mt = 0; mt < 4; ++mt) {
                const int u = mt * 4 + q;
                float iv = sigm_f(acc[mt][0] + bj[mt][0]);
                float fv = sigm_f(acc[mt][1] + bj[mt][1]);
                float gv = tanh_f(acc[mt][2] + bj[mt][2]);
                float ov = sigm_f(acc[mt][3] + bj[mt][3]);
                float cn = fv * cl[u * NB + nn] + iv * gv;
                cl[u * NB + nn] = cn;
                stage[nn * 16 + u] = (bf16_t)(ov * tanh_f(cn));
            }
            __syncthreads();
            if (tid < 256) {   // master write, swizzled, write-through
                const int n = tid >> 1, half = tid & 1;
                u64 v0 = *(const u64*)(stage + n * 16 + half * 8);
                u64 v1 = *(const u64*)(stage + n * 16 + half * 8 + 4);
                size_t unit = ((size_t)((g0 >> 1) * 8 + (n >> 4))) * 64
                              + ((g0 & 1) * 2 + half) * 16 + (n & 15);
                u64* dst = (u64*)(mh0 + (size_t)(t & (DM - 1)) * HB) + unit * 2;
                stw64(dst, v0); stw64(dst + 1, v1);
            }
            __syncthreads();   // drain
            if (tid == 0) stw32(&sync[F0 + g0], (unsigned)(t + 1));
        }
    } else if (b < 128) {
        // ================= X1: W_ih1 @ h0[t] partials =================
        const int g = b - 64;
        for (int c = tid; c < NF1 * 64; c += 512)
            *(bf16x8*)(Wl + (size_t)c * 8) =
                *(const bf16x8*)(Wf1 + ((size_t)g * (NF1 * 64) + c) * 8);
        __syncthreads();

        for (int t = 0; t < T_SEQ; ++t) {
            // wait: f0 all >= t+1 (h0[t] ready); f1 all >= t-(DX-1) (ring guard)
            if (wv == 0) {
                const unsigned tA = (unsigned)(t + 1);
                const unsigned tC = (t >= DX) ? (unsigned)(t - (DX - 1)) : 0u;
                for (;;) {
                    bool ok = (ldcnt(&sync[F0 + lane]) >= tA)
                           && (ldcnt(&sync[F1 + lane]) >= tC)
                           && (ldcnt(&sync[F1 + 64 + lane]) >= tC);
                    if (__all(ok)) break;
                    __builtin_amdgcn_s_sleep(1);
                }
            }
            __syncthreads();
            f32x4 acc[4] = {{0.f,0.f,0.f,0.f},{0.f,0.f,0.f,0.f},{0.f,0.f,0.f,0.f},{0.f,0.f,0.f,0.f}};
            {   // h0[t] panels: depth-32 asm stream, split counted waits
                const bf16_t* B = mh0 + (size_t)(t & (DM - 1)) * HB;
                f32x4 bb[32];
#pragma unroll
                for (int i = 0; i < 32; ++i) {
                    const bf16_t* a = B + (((size_t)i * 8 + wv) * 64 + lane) * 8;
                    GLOAD16(bb[i], a);
                }
                asm volatile("s_waitcnt vmcnt(16)" ::: "memory");
                __builtin_amdgcn_sched_barrier(0);
#pragma unroll
                for (int p = 0; p < 16; ++p) {
                    bf16x8 bv = __builtin_bit_cast(bf16x8, bb[p]);
#pragma unroll
                    for (int mt = 0; mt < 4; ++mt) {
                        bf16x8 av = *(const bf16x8*)(Wl + ((size_t)(p * 4 + mt) * 64 + lane) * 8);
                        acc[mt] = __builtin_amdgcn_mfma_f32_16x16x32_bf16(av, bv, acc[mt], 0, 0, 0);
                    }
                }
                asm volatile("s_waitcnt vmcnt(0)" ::: "memory");
                __builtin_amdgcn_sched_barrier(0);
#pragma unroll
                for (int p = 16; p < 32; ++p) {
                    bf16x8 bv = __builtin_bit_cast(bf16x8, bb[p]);
#pragma unroll
                    for (int mt = 0; mt < 4; ++mt) {
                        bf16x8 av = *(const bf16x8*)(Wl + ((size_t)(p * 4 + mt) * 64 + lane) * 8);
                        acc[mt] = __builtin_amdgcn_mfma_f32_16x16x32_bf16(av, bv, acc[mt], 0, 0, 0);
                    }
                }
            }
            {   // scatter partials: row = u_loc*4 + gate, col = batch
                float* P = x1r + (size_t)(t & (DX - 1)) * X1SLOT + (size_t)g * 64 * NB;
#pragma unroll
                for (int mt = 0; mt < 4; ++mt) {
                    const int u = mt * 4 + q;
#pragma unroll
                    for (int jj = 0; jj < 4; ++jj)
                        stwf(P + (size_t)(u * 4 + jj) * NB + nn, acc[mt][jj]);
                }
            }
            __syncthreads();   // drain partial stores
            if (tid == 0) stw32(&sync[FX + g], (unsigned)(t + 1));
        }
    } else {
        // ================= L1: layer-1 recurrent half =================
        const int g1 = b - 128;
        for (int c = tid; c < NFR * 64; c += 512)
            *(bf16x8*)(Wl + (size_t)c * 8) =
                *(const bf16x8*)(WfR + ((size_t)g1 * (NFR * 64) + c) * 8);
        bf16_t* stage = Wl + L1_STAGE;
        float* cl = (float*)(Wl + L1_STAGE + 1024);      // [8][NB]
        for (int i = tid; i < 8 * NB; i += 512) cl[i] = 0.0f;
        float bj[2][4];
#pragma unroll
        for (int mt = 0; mt < 2; ++mt) {
            const int j = g1 * 8 + mt * 4 + q;
#pragma unroll
            for (int gg = 0; gg < 4; ++gg) bj[mt][gg] = bias1[gg * HID + j];
        }
        __syncthreads();

        for (int t = 0; t < T_SEQ; ++t) {
            // wait: fX[g1>>1] >= t+1 (partials ready); f1 all >= t (own chain)
            if (wv == 0) {
                const unsigned tA = (unsigned)(t + 1);
                const unsigned tO = (unsigned)t;
                const unsigned gx = (unsigned)(g1 >> 1);
                for (;;) {
                    bool ok = (ldcnt(&sync[FX + gx]) >= tA)
                           && (ldcnt(&sync[F1 + lane]) >= tO)
                           && (ldcnt(&sync[F1 + 64 + lane]) >= tO);
                    if (__all(ok)) break;
                    __builtin_amdgcn_s_sleep(1);
                }
            }
            __syncthreads();
            // partials early (drained by the mid-stream vmcnt waits)
            float pv[2][4];
            {
                const float* P = x1r + (size_t)(t & (DX - 1)) * X1SLOT + (size_t)g1 * 32 * NB;
#pragma unroll
                for (int mt = 0; mt < 2; ++mt)
#pragma unroll
                    for (int jj = 0; jj < 4; ++jj)
                        pv[mt][jj] = P[(size_t)((mt * 4 + q) * 4 + jj) * NB + nn];
            }
            f32x4 acc[2] = {{0.f,0.f,0.f,0.f},{0.f,0.f,0.f,0.f}};
            {   // h1[t-1]: depth-32 asm stream, split counted waits
                const bf16_t* B1 = mh1 + (size_t)((t + DM - 1) & (DM - 1)) * HB;
                f32x4 bb[32];
#pragma unroll
                for (int i = 0; i < 32; ++i) {
                    const bf16_t* a = B1 + (((size_t)i * 8 + wv) * 64 + lane) * 8;
                    GLOAD16(bb[i], a);
                }
                asm volatile("s_waitcnt vmcnt(16)" ::: "memory");
                __builtin_amdgcn_sched_barrier(0);
#pragma unroll
                for (int p = 0; p < 16; ++p) {
                    bf16x8 bv = __builtin_bit_cast(bf16x8, bb[p]);
#pragma unroll
                    for (int mt = 0; mt < 2; ++mt) {
                        bf16x8 av = *(const bf16x8*)(Wl + ((size_t)(p * 2 + mt) * 64 + lane) * 8);
                        acc[mt] = __builtin_amdgcn_mfma_f32_16x16x32_bf16(av, bv, acc[mt], 0, 0, 0);
                    }
                }
                asm volatile("s_waitcnt vmcnt(0)" ::: "memory");
                __builtin_amdgcn_sched_barrier(0);
#pragma unroll
                for (int p = 16; p < 32; ++p) {
                    bf16x8 bv = __builtin_bit_cast(bf16x8, bb[p]);
#pragma unroll
                    for (int mt = 0; mt < 2; ++mt) {
                        bf16x8 av = *(const bf16x8*)(Wl + ((size_t)(p * 2 + mt) * 64 + lane) * 8);
                        acc[mt] = __builtin_amdgcn_mfma_f32_16x16x32_bf16(av, bv, acc[mt], 0, 0, 0);
                    }
                }
            }
#pragma unroll
            for (int mt = 0; mt < 2; ++mt) {
                const int u = mt * 4 + q;
                float iv = sigm_f(acc[mt][0] + pv[mt][0] + bj[mt][0]);
                float fv = sigm_f(acc[mt][1] + pv[mt][1] + bj[mt][1]);
                float gv = tanh_f(acc[mt][2] + pv[mt][2] + bj[mt][2]);
                float ov = sigm_f(acc[mt][3] + pv[mt][3] + bj[mt][3]);
                float cn = fv * cl[u * NB + nn] + iv * gv;
                cl[u * NB + nn] = cn;
                stage[nn * 8 + u] = (bf16_t)(ov * tanh_f(cn));
            }
            __asm__ volatile("s_waitcnt lgkmcnt(0)" ::: "memory");  // own-wave LDS done
            u64 v = 0;
            if (q < 2) {   // per-wave master write (stage rows are wave-owned)
                v = *(const u64*)(stage + (size_t)(wv * 16 + l) * 8 + q * 4);
                size_t unit = ((size_t)(g1 >> 2) * 8 + wv) * 64 + (size_t)(g1 & 3) * 16 + l;
                stw64((u64*)(mh1 + (size_t)(t & (DM - 1)) * HB) + unit * 2 + q, v);
            }
            __syncthreads();   // drain all waves' master stores
            if (tid == 0) stw32(&sync[F1 + g1], (unsigned)(t + 1));
            if (q < 2)     // h2 history after flag (off the chain)
                *(u64*)(h2buf + ((size_t)(wv * 16 + l) * T_SEQ + t) * HID + g1 * 8 + q * 4) = v;
        }
    }
}

__global__ __launch_bounds__(256) void fc_kernel(
    const bf16_t* __restrict__ h2buf, const bf16_t* __restrict__ Wfcb,
    const float* __restrict__ bfc, float* __restrict__ out)
{
    const int tid = threadIdx.x, wv = tid >> 6, lane = tid & 63;
    const int q = lane >> 4, l = lane & 15;
    const int m0 = blockIdx.x * 64 + wv * 16;
    const bf16_t* arow = h2buf + (size_t)(m0 + l) * HID + q * 8;
    const bf16_t* brow = Wfcb + (size_t)l * HID + q * 8;
    f32x4 acc[4] = {{0.f,0.f,0.f,0.f},{0.f,0.f,0.f,0.f},{0.f,0.f,0.f,0.f},{0.f,0.f,0.f,0.f}};
#pragma unroll 4
    for (int p = 0; p < 32; ++p) {
        bf16x8 av = *(const bf16x8*)(arow + p * 32);
#pragma unroll
        for (int ntile = 0; ntile < 4; ++ntile) {
            bf16x8 bv = *(const bf16x8*)(brow + (size_t)ntile * 16 * HID + p * 32);
            acc[ntile] = __builtin_amdgcn_mfma_f32_16x16x32_bf16(av, bv, acc[ntile], 0, 0, 0);
        }
    }
#pragma unroll
    for (int ntile = 0; ntile < 4; ++ntile) {
        float bv = bfc[ntile * 16 + l];
#pragma unroll
        for (int r = 0; r < 4; ++r)
            out[(size_t)(m0 + q * 4 + r) * 64 + ntile * 16 + l] = acc[ntile][r] + bv;
    }
}

extern "C" void kernel_launch(void* const* d_in, const int* in_sizes, int n_in,
                              void* d_out, int out_size, void* d_ws, size_t ws_size,
                              hipStream_t stream)
{
    const float* x    = (const float*)d_in[0];
    const float* Wih0 = (const float*)d_in[1];
    const float* Whh0 = (const float*)d_in[2];
    const float* bih0 = (const float*)d_in[3];
    const float* bhh0 = (const float*)d_in[4];
    const float* Wih1 = (const float*)d_in[5];
    const float* Whh1 = (const float*)d_in[6];
    const float* bih1 = (const float*)d_in[7];
    const float* bhh1 = (const float*)d_in[8];
    const float* Wfc  = (const float*)d_in[9];
    const float* bfc  = (const float*)d_in[10];
    float* out = (float*)d_out;

    char* ws = (char*)d_ws;
    size_t off = 0;
    auto alloc = [&](size_t bytes) -> void* {
        void* p = ws + off;
        off += (bytes + 255) & ~(size_t)255;
        return p;
    };
    bf16_t* Wf0  = (bf16_t*)alloc((size_t)64 * NF0 * 64 * 8 * 2);
    bf16_t* Wf1  = (bf16_t*)alloc((size_t)64 * NF1 * 64 * 8 * 2);
    bf16_t* WfR  = (bf16_t*)alloc((size_t)128 * NFR * 64 * 8 * 2);
    bf16_t* xswz = (bf16_t*)alloc((size_t)NB * T_SEQ * FIN * 2);
    bf16_t* h2buf= (bf16_t*)alloc((size_t)NB * T_SEQ * HID * 2);
    bf16_t* mh0  = (bf16_t*)alloc((size_t)DM * HB * 2);
    bf16_t* mh1  = (bf16_t*)alloc((size_t)DM * HB * 2);
    float*  x1r  = (float*)alloc((size_t)DX * X1SLOT * 4);
    float*  bias0= (float*)alloc(4096 * 4);
    float*  bias1= (float*)alloc(4096 * 4);
    bf16_t* Wfcb = (bf16_t*)alloc((size_t)64 * HID * 2);
    unsigned* syncp = (unsigned*)alloc(SYNC_N * 4);
    if (off > ws_size) return;

    hipFuncSetAttribute((const void*)lstm_persist,
                        hipFuncAttributeMaxDynamicSharedMemorySize, LDS_BYTES);

    prep_kernel<<<1024, 256, 0, stream>>>(x, Wih0, Whh0, bih0, bhh0,
                                          Wih1, Whh1, bih1, bhh1, Wfc,
                                          Wf0, Wf1, WfR, xswz, Wfcb,
                                          bias0, bias1, mh0, mh1, syncp);

    void* args[] = { (void*)&Wf0, (void*)&Wf1, (void*)&WfR,
                     (void*)&bias0, (void*)&bias1,
                     (void*)&xswz, (void*)&mh0, (void*)&mh1,
                     (void*)&h2buf, (void*)&x1r,
                     (void*)&syncp };
    hipLaunchCooperativeKernel((void*)lstm_persist, dim3(NBLK), dim3(512),
                               args, LDS_BYTES, stream);

    fc_kernel<<<(NB * T_SEQ) / 64, 256, 0, stream>>>(h2buf, Wfcb, bfc, out);
}

// Round 9
// 4305.112 us; speedup vs baseline: 1.1958x; 1.1613x over previous
//
#include <hip/hip_runtime.h>
#include <hip/hip_bf16.h>

typedef __bf16 bf16_t;
typedef bf16_t bf16x8 __attribute__((ext_vector_type(8)));
typedef float f32x4 __attribute__((ext_vector_type(4)));
typedef unsigned long long u64;

#define T_SEQ 512
#define NB 128
#define HID 1024
#define FIN 64
#define LD0 1088                 // 64 + 1024
#define LD1 2048                 // 1024 + 1024
#define HB (NB * HID)            // 131072 elems = 256 KB per h snapshot
#define ST0 1096                 // L0 LDS weight row stride (elems, K=1088)
#define STX 1032                 // X1/L1 LDS weight row stride (elems, K=1024)
#define NBLK 256                 // 64 L0 + 64 X1 + 128 L1  (all 256 CUs)
#define DM 32                    // master h ring depth
#define DX 8                     // X1 partial ring depth (2 MB f32 / slot)
#define X1SLOT (4096 * NB)       // floats per X1 slot: [4096 gate-rows][128 batch]
#define LDS_BYTES (64 * ST0 * 2 + 4096)   // weights + stage (L0 role is max)

// sync[]: per-block completion flags (value = steps completed).
#define F0 0      // f0[64]:  L0 block flags
#define FX 64     // fX[64]:  X1 block flags
#define F1 128    // f1[128]: L1 block flags
#define SYNC_N 256

__device__ __forceinline__ float sigm_f(float x) { return 1.0f / (1.0f + __expf(-x)); }
__device__ __forceinline__ float tanh_f(float x) { return 2.0f * sigm_f(2.0f * x) - 1.0f; }

__device__ __forceinline__ unsigned ldcnt(const unsigned* p) {
    return __hip_atomic_load(p, __ATOMIC_RELAXED, __HIP_MEMORY_SCOPE_AGENT);
}
__device__ __forceinline__ void stw32(unsigned* p, unsigned v) {   // write-through
    __hip_atomic_store(p, v, __ATOMIC_RELAXED, __HIP_MEMORY_SCOPE_AGENT);
}
__device__ __forceinline__ void stwf(float* p, float v) {          // write-through f32
    __hip_atomic_store(p, v, __ATOMIC_RELAXED, __HIP_MEMORY_SCOPE_AGENT);
}
__device__ __forceinline__ void stw64(u64* p, u64 v) {
    __hip_atomic_store(p, v, __ATOMIC_RELAXED, __HIP_MEMORY_SCOPE_AGENT);
}

// Fragment-swizzled h layout: 16B unit = (panel*8 + wv)*64 + lane, holding
// h[n = wv*16 + (lane&15)][k = panel*32 + (lane>>4)*8 .. +8].

__global__ __launch_bounds__(256) void prep_kernel(
    const float* __restrict__ x,
    const float* __restrict__ Wih0, const float* __restrict__ Whh0,
    const float* __restrict__ bih0, const float* __restrict__ bhh0,
    const float* __restrict__ Wih1, const float* __restrict__ Whh1,
    const float* __restrict__ bih1, const float* __restrict__ bhh1,
    const float* __restrict__ Wfc,
    bf16_t* __restrict__ Wcat0, bf16_t* __restrict__ Wcat1,
    bf16_t* __restrict__ xswz, bf16_t* __restrict__ Wfcb,
    float* __restrict__ bias0, float* __restrict__ bias1,
    bf16_t* __restrict__ mh0, bf16_t* __restrict__ mh1,
    float* __restrict__ c0, float* __restrict__ c1,
    unsigned* __restrict__ sync)
{
    const unsigned stride = gridDim.x * blockDim.x;
    const unsigned i0 = blockIdx.x * blockDim.x + threadIdx.x;

    for (unsigned i = i0; i < SYNC_N; i += stride) sync[i] = 0u;

    for (unsigned i = i0; i < 4096u * LD1; i += stride) {
        unsigned m = i >> 11, kk = i & 2047u;
        float v = (kk < HID) ? Wih1[m * HID + kk] : Whh1[m * HID + (kk - HID)];
        Wcat1[i] = (bf16_t)v;
    }
    for (unsigned i = i0; i < 4096u * LD0; i += stride) {
        unsigned m = i / LD0, kk = i - m * LD0;
        float v = (kk < FIN) ? Wih0[m * FIN + kk] : Whh0[m * HID + (kk - FIN)];
        Wcat0[i] = (bf16_t)v;
    }
    // x into fragment-swizzled layout
    for (unsigned i = i0; i < 4194304u; i += stride) {   // 128*512*64
        unsigned e = i & 7u, unit = i >> 3;
        unsigned lane = unit & 63u, g = unit >> 6;
        unsigned wvv = g & 7u, pt = g >> 3;              // pt = t*2 + p
        unsigned p = pt & 1u, t = pt >> 1;
        unsigned n = wvv * 16u + (lane & 15u);
        unsigned k = p * 32u + (lane >> 4) * 8u + e;
        xswz[i] = (bf16_t)x[((size_t)n * T_SEQ + t) * FIN + k];
    }
    for (unsigned i = i0; i < 64u * HID; i += stride)
        Wfcb[i] = (bf16_t)Wfc[i];
    for (unsigned i = i0; i < (unsigned)(DM * HB); i += stride) {
        mh0[i] = (bf16_t)0.0f; mh1[i] = (bf16_t)0.0f;    // slot DM-1 read as h[-1]=0
    }
    for (unsigned i = i0; i < (unsigned)HB; i += stride) { c0[i] = 0.0f; c1[i] = 0.0f; }
    for (unsigned i = i0; i < 4096u; i += stride) {
        bias0[i] = bih0[i] + bhh0[i];
        bias1[i] = bih1[i] + bhh1[i];
    }
}

// Persistent cooperative kernel: 256 blocks x 512 threads, 1 block/CU.
// Blocks 0..63   = L0: recurrence of layer 0 (rows=16 units x 4 gates, K=1088).
// Blocks 64..127 = X1: input-half partials of layer 1, W_ih1 @ h0[t]
//                  (rows=16 units x 4 gates, K=1024) -> f32 ring, DX deep.
//                  Runs ~DX steps ahead of L1 (pipelined off the chain).
// Blocks 128..255= L1: recurrent half only, acc init from X1 partials
//                  (rows=8 units x 4 gates, K=1024).
// Producers write rings with write-through atomics; consumers use PLAIN
// coalesced loads (XCD L2 aggregates; ring depth >> L2 slot lifetime).
__global__ __launch_bounds__(512) void lstm_persist(
    const bf16_t* __restrict__ Wcat0, const bf16_t* __restrict__ Wcat1,
    const float* __restrict__ bias0, const float* __restrict__ bias1,
    const bf16_t* __restrict__ xswz,
    bf16_t* __restrict__ mh0,   // [DM][HB] master h0 ring (swizzled)
    bf16_t* __restrict__ mh1,   // [DM][HB] master h1 ring (swizzled)
    float* __restrict__ c0, float* __restrict__ c1,   // [HID][NB], block-private
    bf16_t* __restrict__ h2buf, // [NB][T][HID] layer1 history for FC
    float* __restrict__ x1r,    // [DX][4096][NB] f32 partial preactivation ring
    unsigned* __restrict__ sync)
{
    extern __shared__ bf16_t Wl[];
    const int b = blockIdx.x;
    const int tid = threadIdx.x;
    const int layer = (b >= 64);

    // ---- one-time weight gather into LDS (rows ordered u*4+gate) ----
    bf16_t* stage;
    if (b < 64) {
        const int g0 = b;
        for (int c = tid; c < 64 * (LD0 / 8); c += 512) {
            int r = c / (LD0 / 8), off = (c % (LD0 / 8)) * 8;
            int u = r >> 2, gate = r & 3;
            *(bf16x8*)(Wl + r * ST0 + off) =
                *(const bf16x8*)(Wcat0 + (size_t)(gate * HID + g0 * 16 + u) * LD0 + off);
        }
        stage = Wl + 64 * ST0;
    } else if (b < 128) {
        const int g = b - 64;
        for (int c = tid; c < 64 * 128; c += 512) {      // 64 rows x 128 octets (Wih1)
            int r = c >> 7, off = (c & 127) * 8;
            int u = r >> 2, gate = r & 3;
            *(bf16x8*)(Wl + r * STX + off) =
                *(const bf16x8*)(Wcat1 + (size_t)(gate * HID + g * 16 + u) * LD1 + off);
        }
        stage = Wl + 64 * STX;
    } else {
        const int g1 = b - 128;
        for (int c = tid; c < 32 * 128; c += 512) {      // Whh1 only (cols 1024..2047)
            int r = c >> 7, off = (c & 127) * 8;
            int u = r >> 2, gate = r & 3;
            *(bf16x8*)(Wl + r * STX + off) =
                *(const bf16x8*)(Wcat1 + (size_t)(gate * HID + g1 * 8 + u) * LD1 + HID + off);
        }
        stage = Wl + 32 * STX;
    }
    __syncthreads();

    const int wv = tid >> 6;
    const int lane = tid & 63;
    const int q = lane >> 4;
    const int l = lane & 15;
    const int nn = wv * 16 + l;

    if (b < 64) {
        // ================= L0: layer-0 recurrence =================
        const int g0 = b;
        for (int t = 0; t < T_SEQ; ++t) {
            if (t >= DM) {       // mh0 slot-overwrite guard (X1 must have read t-32)
                // folded into the wait below via tB
            }
            f32x4 acc[4] = {{0.f,0.f,0.f,0.f},{0.f,0.f,0.f,0.f},{0.f,0.f,0.f,0.f},{0.f,0.f,0.f,0.f}};
            // x panels: no dependency, compute BEFORE the wait
            {
                const bf16_t* X = xswz + (((size_t)t * 2) * 8) * 64 * 8;
#pragma unroll
                for (int p = 0; p < 2; ++p) {
                    bf16x8 bv = *(const bf16x8*)(X + (((size_t)p * 8 + wv) * 64 + lane) * 8);
#pragma unroll
                    for (int mt = 0; mt < 4; ++mt) {
                        bf16x8 av = *(const bf16x8*)(Wl + (mt * 16 + l) * ST0 + p * 32 + q * 8);
                        acc[mt] = __builtin_amdgcn_mfma_f32_16x16x32_bf16(av, bv, acc[mt], 0, 0, 0);
                    }
                }
            }
            // wait: f0 all >= t (own chain); fX all >= t-31 (mh0 ring guard)
            __syncthreads();
            if (wv == 0) {
                const unsigned tA = (unsigned)t;
                const unsigned tB = (t >= DM) ? (unsigned)(t - (DM - 1)) : 0u;
                for (;;) {
                    bool ok = (ldcnt(&sync[F0 + lane]) >= tA)
                           && (ldcnt(&sync[FX + lane]) >= tB);
                    if (__all(ok)) break;
                    __builtin_amdgcn_s_sleep(1);
                }
            }
            __syncthreads();
            // h panels from mh0 slot (t-1): plain coalesced loads
            {
                const bf16_t* B = mh0 + (size_t)((t + DM - 1) & (DM - 1)) * HB;
                bf16x8 bb[16];
#pragma unroll
                for (int i = 0; i < 16; ++i)
                    bb[i] = *(const bf16x8*)(B + (((size_t)i * 8 + wv) * 64 + lane) * 8);
#pragma unroll
                for (int p = 0; p < 32; ++p) {
                    bf16x8 bv = bb[p & 15];
#pragma unroll
                    for (int mt = 0; mt < 4; ++mt) {
                        bf16x8 av = *(const bf16x8*)(Wl + (mt * 16 + l) * ST0 + FIN + p * 32 + q * 8);
                        acc[mt] = __builtin_amdgcn_mfma_f32_16x16x32_bf16(av, bv, acc[mt], 0, 0, 0);
                    }
                    if (p + 16 < 32)
                        bb[p & 15] = *(const bf16x8*)(B + (((size_t)(p + 16) * 8 + wv) * 64 + lane) * 8);
                }
            }
            // lane-local cell update -> stage
#pragma unroll
            for (int mt = 0; mt < 4; ++mt) {
                const int u = mt * 4 + q, j = g0 * 16 + u;
                float iv = sigm_f(acc[mt][0] + bias0[j]);
                float fv = sigm_f(acc[mt][1] + bias0[HID + j]);
                float gv = tanh_f(acc[mt][2] + bias0[2 * HID + j]);
                float ov = sigm_f(acc[mt][3] + bias0[3 * HID + j]);
                const size_t ci = (size_t)j * NB + nn;
                float cn = fv * c0[ci] + iv * gv;
                c0[ci] = cn;
                stage[nn * 16 + u] = (bf16_t)(ov * tanh_f(cn));
            }
            __syncthreads();
            if (tid < 256) {   // master write, swizzled, write-through
                const int n = tid >> 1, half = tid & 1;
                u64 v0 = *(const u64*)(stage + n * 16 + half * 8);
                u64 v1 = *(const u64*)(stage + n * 16 + half * 8 + 4);
                size_t unit = ((size_t)((g0 >> 1) * 8 + (n >> 4))) * 64
                              + ((g0 & 1) * 2 + half) * 16 + (n & 15);
                u64* dst = (u64*)(mh0 + (size_t)(t & (DM - 1)) * HB) + unit * 2;
                stw64(dst, v0); stw64(dst + 1, v1);
            }
            __syncthreads();   // all waves' stores drained (vmcnt 0 at barrier)
            if (tid == 0) stw32(&sync[F0 + g0], (unsigned)(t + 1));
        }
    } else if (b < 128) {
        // ================= X1: W_ih1 @ h0[t] partials =================
        const int g = b - 64;   // 16 units: u_global in [g*16, g*16+16)
        for (int t = 0; t < T_SEQ; ++t) {
            // wait: f0 all >= t+1 (h0[t] ready); f1 all >= t-(DX-1) (ring guard)
            __syncthreads();
            if (wv == 0) {
                const unsigned tA = (unsigned)(t + 1);
                const unsigned tC = (t >= DX) ? (unsigned)(t - (DX - 1)) : 0u;
                for (;;) {
                    bool ok = (ldcnt(&sync[F0 + lane]) >= tA)
                           && (ldcnt(&sync[F1 + lane]) >= tC)
                           && (ldcnt(&sync[F1 + 64 + lane]) >= tC);
                    if (__all(ok)) break;
                    __builtin_amdgcn_s_sleep(1);
                }
            }
            __syncthreads();
            f32x4 acc[4] = {{0.f,0.f,0.f,0.f},{0.f,0.f,0.f,0.f},{0.f,0.f,0.f,0.f},{0.f,0.f,0.f,0.f}};
            {
                const bf16_t* B = mh0 + (size_t)(t & (DM - 1)) * HB;
                bf16x8 bb[16];
#pragma unroll
                for (int i = 0; i < 16; ++i)
                    bb[i] = *(const bf16x8*)(B + (((size_t)i * 8 + wv) * 64 + lane) * 8);
#pragma unroll
                for (int p = 0; p < 32; ++p) {
                    bf16x8 bv = bb[p & 15];
#pragma unroll
                    for (int mt = 0; mt < 4; ++mt) {
                        bf16x8 av = *(const bf16x8*)(Wl + (mt * 16 + l) * STX + p * 32 + q * 8);
                        acc[mt] = __builtin_amdgcn_mfma_f32_16x16x32_bf16(av, bv, acc[mt], 0, 0, 0);
                    }
                    if (p + 16 < 32)
                        bb[p & 15] = *(const bf16x8*)(B + (((size_t)(p + 16) * 8 + wv) * 64 + lane) * 8);
                }
            }
            // scatter partials (f32, write-through): row = (u_loc*4 + gate)
            {
                float* P = x1r + (size_t)(t & (DX - 1)) * X1SLOT + (size_t)g * 64 * NB;
#pragma unroll
                for (int mt = 0; mt < 4; ++mt)
#pragma unroll
                    for (int j = 0; j < 4; ++j)
                        stwf(P + (size_t)((mt * 4 + q) * 4 + j) * NB + nn, acc[mt][j]);
            }
            __syncthreads();   // drain partial stores
            if (tid == 0) stw32(&sync[FX + g], (unsigned)(t + 1));
        }
    } else {
        // ================= L1: layer-1 recurrent half =================
        const int g1 = b - 128;  // 8 units: u_global in [g1*8, g1*8+8)
        for (int t = 0; t < T_SEQ; ++t) {
            // wait: fX[g1>>1] >= t+1 (partials ready); f1 all >= t (own chain)
            __syncthreads();
            if (wv == 0) {
                const unsigned tA = (unsigned)(t + 1);
                const unsigned tO = (unsigned)t;
                const unsigned gx = (unsigned)(g1 >> 1);
                for (;;) {
                    bool ok = (ldcnt(&sync[FX + gx]) >= tA)
                           && (ldcnt(&sync[F1 + lane]) >= tO)
                           && (ldcnt(&sync[F1 + 64 + lane]) >= tO);
                    if (__all(ok)) break;
                    __builtin_amdgcn_s_sleep(1);
                }
            }
            __syncthreads();
            // acc init from X1 partials (8 x f32 per lane)
            f32x4 acc[2];
            {
                const float* P = x1r + (size_t)(t & (DX - 1)) * X1SLOT + (size_t)g1 * 32 * NB;
#pragma unroll
                for (int mt = 0; mt < 2; ++mt)
#pragma unroll
                    for (int j = 0; j < 4; ++j)
                        acc[mt][j] = P[(size_t)((mt * 4 + q) * 4 + j) * NB + nn];
            }
            // h1[t-1] recurrent half (K=1024)
            {
                const bf16_t* B1 = mh1 + (size_t)((t + DM - 1) & (DM - 1)) * HB;
                bf16x8 bb[16];
#pragma unroll
                for (int i = 0; i < 16; ++i)
                    bb[i] = *(const bf16x8*)(B1 + (((size_t)i * 8 + wv) * 64 + lane) * 8);
#pragma unroll
                for (int p = 0; p < 32; ++p) {
                    bf16x8 bv = bb[p & 15];
#pragma unroll
                    for (int mt = 0; mt < 2; ++mt) {
                        bf16x8 av = *(const bf16x8*)(Wl + (mt * 16 + l) * STX + p * 32 + q * 8);
                        acc[mt] = __builtin_amdgcn_mfma_f32_16x16x32_bf16(av, bv, acc[mt], 0, 0, 0);
                    }
                    if (p + 16 < 32)
                        bb[p & 15] = *(const bf16x8*)(B1 + (((size_t)(p + 16) * 8 + wv) * 64 + lane) * 8);
                }
            }
#pragma unroll
            for (int mt = 0; mt < 2; ++mt) {
                const int u = mt * 4 + q, j = g1 * 8 + u;
                float iv = sigm_f(acc[mt][0] + bias1[j]);
                float fv = sigm_f(acc[mt][1] + bias1[HID + j]);
                float gv = tanh_f(acc[mt][2] + bias1[2 * HID + j]);
                float ov = sigm_f(acc[mt][3] + bias1[3 * HID + j]);
                const size_t ci = (size_t)j * NB + nn;
                float cn = fv * c1[ci] + iv * gv;
                c1[ci] = cn;
                stage[nn * 8 + u] = (bf16_t)(ov * tanh_f(cn));
            }
            __syncthreads();
            if (tid < 128) {   // master write (swizzled, write-through)
                const int n = tid;
                u64 v0 = *(const u64*)(stage + n * 8);
                u64 v1 = *(const u64*)(stage + n * 8 + 4);
                size_t unit = ((size_t)((g1 >> 2) * 8 + (n >> 4))) * 64
                              + (g1 & 3) * 16 + (n & 15);
                u64* dst = (u64*)(mh1 + (size_t)(t & (DM - 1)) * HB) + unit * 2;
                stw64(dst, v0); stw64(dst + 1, v1);
            }
            __syncthreads();   // master stores drained
            if (tid == 0) stw32(&sync[F1 + g1], (unsigned)(t + 1));
            if (tid < 256) {   // h2 history AFTER flag (off the drain path)
                const int n = tid >> 1, part = tid & 1;
                *(u64*)(h2buf + ((size_t)n * T_SEQ + t) * HID + g1 * 8 + part * 4) =
                    *(const u64*)(stage + n * 8 + part * 4);
            }
        }
    }
}

// Final FC: out[m][o] = h2[m][:] @ Wfc[o][:] + bfc[o], m = n*T + t.
__global__ __launch_bounds__(256) void fc_kernel(
    const bf16_t* __restrict__ h2buf, const bf16_t* __restrict__ Wfcb,
    const float* __restrict__ bfc, float* __restrict__ out)
{
    const int tid = threadIdx.x, wv = tid >> 6, lane = tid & 63;
    const int q = lane >> 4, l = lane & 15;
    const int m0 = blockIdx.x * 64 + wv * 16;
    const bf16_t* arow = h2buf + (size_t)(m0 + l) * HID + q * 8;
    const bf16_t* brow = Wfcb + (size_t)l * HID + q * 8;
    f32x4 acc[4] = {{0.f,0.f,0.f,0.f},{0.f,0.f,0.f,0.f},{0.f,0.f,0.f,0.f},{0.f,0.f,0.f,0.f}};
#pragma unroll 4
    for (int p = 0; p < 32; ++p) {
        bf16x8 av = *(const bf16x8*)(arow + p * 32);
#pragma unroll
        for (int ntile = 0; ntile < 4; ++ntile) {
            bf16x8 bv = *(const bf16x8*)(brow + (size_t)ntile * 16 * HID + p * 32);
            acc[ntile] = __builtin_amdgcn_mfma_f32_16x16x32_bf16(av, bv, acc[ntile], 0, 0, 0);
        }
    }
#pragma unroll
    for (int ntile = 0; ntile < 4; ++ntile) {
        float bv = bfc[ntile * 16 + l];
#pragma unroll
        for (int r = 0; r < 4; ++r)
            out[(size_t)(m0 + q * 4 + r) * 64 + ntile * 16 + l] = acc[ntile][r] + bv;
    }
}

extern "C" void kernel_launch(void* const* d_in, const int* in_sizes, int n_in,
                              void* d_out, int out_size, void* d_ws, size_t ws_size,
                              hipStream_t stream)
{
    const float* x    = (const float*)d_in[0];
    const float* Wih0 = (const float*)d_in[1];
    const float* Whh0 = (const float*)d_in[2];
    const float* bih0 = (const float*)d_in[3];
    const float* bhh0 = (const float*)d_in[4];
    const float* Wih1 = (const float*)d_in[5];
    const float* Whh1 = (const float*)d_in[6];
    const float* bih1 = (const float*)d_in[7];
    const float* bhh1 = (const float*)d_in[8];
    const float* Wfc  = (const float*)d_in[9];
    const float* bfc  = (const float*)d_in[10];
    float* out = (float*)d_out;

    char* ws = (char*)d_ws;
    size_t off = 0;
    auto alloc = [&](size_t bytes) -> void* {
        void* p = ws + off;
        off += (bytes + 255) & ~(size_t)255;
        return p;
    };
    bf16_t* Wcat0 = (bf16_t*)alloc((size_t)4096 * LD0 * 2);           // 8.9 MB
    bf16_t* Wcat1 = (bf16_t*)alloc((size_t)4096 * LD1 * 2);           // 16.8 MB
    bf16_t* xswz  = (bf16_t*)alloc((size_t)NB * T_SEQ * FIN * 2);     // 8.4 MB
    bf16_t* h2buf = (bf16_t*)alloc((size_t)NB * T_SEQ * HID * 2);     // 134 MB
    bf16_t* mh0   = (bf16_t*)alloc((size_t)DM * HB * 2);              // 8.4 MB
    bf16_t* mh1   = (bf16_t*)alloc((size_t)DM * HB * 2);              // 8.4 MB
    float*  x1r   = (float*)alloc((size_t)DX * X1SLOT * 4);           // 16.8 MB
    float*  c0    = (float*)alloc((size_t)HB * 4);
    float*  c1    = (float*)alloc((size_t)HB * 4);
    float*  bias0 = (float*)alloc(4096 * 4);
    float*  bias1 = (float*)alloc(4096 * 4);
    bf16_t* Wfcb  = (bf16_t*)alloc((size_t)64 * HID * 2);
    unsigned* syncp = (unsigned*)alloc(SYNC_N * 4);
    if (off > ws_size) return;

    hipFuncSetAttribute((const void*)lstm_persist,
                        hipFuncAttributeMaxDynamicSharedMemorySize, LDS_BYTES);

    prep_kernel<<<1024, 256, 0, stream>>>(x, Wih0, Whh0, bih0, bhh0,
                                          Wih1, Whh1, bih1, bhh1, Wfc,
                                          Wcat0, Wcat1, xswz, Wfcb,
                                          bias0, bias1, mh0, mh1,
                                          c0, c1, syncp);

    void* args[] = { (void*)&Wcat0, (void*)&Wcat1, (void*)&bias0, (void*)&bias1,
                     (void*)&xswz, (void*)&mh0, (void*)&mh1,
                     (void*)&c0, (void*)&c1, (void*)&h2buf, (void*)&x1r,
                     (void*)&syncp };
    hipLaunchCooperativeKernel((void*)lstm_persist, dim3(NBLK), dim3(512),
                               args, LDS_BYTES, stream);

    fc_kernel<<<(NB * T_SEQ) / 64, 256, 0, stream>>>(h2buf, Wfcb, bfc, out);
}